// Round 5
// baseline (6815.143 us; speedup 1.0000x reference)
//
#include <hip/hip_runtime.h>

typedef unsigned short u16;
typedef unsigned int   u32;
typedef _Float16 f16;
typedef f16   f16x2 __attribute__((ext_vector_type(2)));
typedef f16   f16x8 __attribute__((ext_vector_type(8)));
typedef float f32x4 __attribute__((ext_vector_type(4)));
typedef u32   u32x4 __attribute__((ext_vector_type(4)));

#define B_  64
#define L_  384
#define CS  512   // SRC_DIM
#define H_  512
#define E_  256
#define NC  250
#define T_  127
#define XROW 1024  // fallback X row: [ctx(512) | h(512)] f16
#define XEH  768   // new-path X row: [emb(256) | h(512)] f16

__device__ __forceinline__ float h2f(u16 u){ f16 h; __builtin_memcpy(&h,&u,2); return (float)h; }
__device__ __forceinline__ u16  f2h(float f){ f16 h=(f16)f; u16 u; __builtin_memcpy(&u,&h,2); return u; }
__device__ __forceinline__ float wredsum(float v){
#pragma unroll
  for (int o=32;o>0;o>>=1) v += __shfl_down(v, o, 64);
  return v;
}
__device__ __forceinline__ float tanh_f(float x){
  x = fminf(fmaxf(x, -15.f), 15.f);
  float e = __expf(2.f*x);
  return (e-1.f)/(e+1.f);
}
__device__ __forceinline__ float sigm_f(float x){
  x = fminf(fmaxf(x, -30.f), 30.f);
  return 1.f/(1.f+__expf(-x));
}
__device__ __forceinline__ float dot2f(u32 a, u32 b, float c){
  f16x2 x, y; __builtin_memcpy(&x,&a,4); __builtin_memcpy(&y,&b,4);
#if __has_builtin(__builtin_amdgcn_fdot2)
  return __builtin_amdgcn_fdot2(x, y, c, false);
#else
  return c + (float)x[0]*(float)y[0] + (float)x[1]*(float)y[1];
#endif
}

// ---------------- one-time converters ----------------
__global__ __launch_bounds__(256) void k_cvt(const float* __restrict__ in, f16* __restrict__ o, int n){
  int i = blockIdx.x*256 + threadIdx.x;
  if (i < n) o[i] = (f16)in[i];
}

// Quad-k-pair-packed Wh2h (verified round 4):
// WhQ[((kq*512)+n)*4 + e] = (Wh2h[n][8kq+2e], Wh2h[n][8kq+2e+1]) as f16-pair u32.
__global__ __launch_bounds__(256) void k_packwhq(const float* __restrict__ Wh, u32* __restrict__ Wq){
  int i = blockIdx.x*256 + threadIdx.x;   // over 64*512*4
  if (i < 64*512*4){
    int kq = i >> 11, n = (i >> 2) & 511, e = i & 3;
    int k = kq*8 + e*2;
    u32 lo = f2h(Wh[(size_t)n*512 + k]);
    u32 hi = f2h(Wh[(size_t)n*512 + k + 1]);
    Wq[i] = lo | (hi<<16);
  }
}

// NEW: ctx-part gates weights, row pc = hd*4+g  <->  orig row r = g*512+hd; cols k in [0,512).
__global__ __launch_bounds__(256) void k_packwcp(const float* __restrict__ Wih, f16* __restrict__ Wcp){
  int i = blockIdx.x*256 + threadIdx.x;   // over 2048*512
  if (i < 2048*512){
    int pc = i >> 9, k = i & 511;
    int r = (pc&3)*512 + (pc>>2);
    Wcp[i] = (f16)Wih[(size_t)r*768 + k];
  }
}

// NEW: [emb|h]-part gates weights. WgP[pc][k'] with r=(pc&3)*512+(pc>>2):
// k'<256 -> W_ih[r][512+k'] ; k'>=256 -> W_hh[r][k'-256]. bias_g[pc]=bih[r]+bhh[r].
__global__ __launch_bounds__(256) void k_packwgp2(const float* __restrict__ Wih,
    const float* __restrict__ Whh, const float* __restrict__ bih, const float* __restrict__ bhh,
    f16* __restrict__ WgP, float* __restrict__ bias_g){
  int i = blockIdx.x*256 + threadIdx.x;   // over 2048*768
  if (i < 2048*768){
    int pc = i / 768, k = i - pc*768;
    int r = (pc&3)*512 + (pc>>2);
    float v = (k < 256) ? Wih[(size_t)r*768 + 512 + k] : Whh[(size_t)r*512 + (k-256)];
    WgP[i] = (f16)v;
    if (k == 0) bias_g[pc] = bih[r] + bhh[r];
  }
}

// Fallback: permuted gates-weight pack (verified round 2).
__global__ __launch_bounds__(256) void k_packwg(const float* __restrict__ Wih,
    const float* __restrict__ Whh, const float* __restrict__ bih, const float* __restrict__ bhh,
    f16* __restrict__ Wg, float* __restrict__ bias_g){
  int i = blockIdx.x*256 + threadIdx.x;   // over 2048*1280
  if (i < 2048*1280){
    int p = i / 1280, c = i - p*1280;
    int j = p >> 4, q = p & 15, g = q >> 2, hl = q & 3;
    int r = g*512 + (j<<2) + hl;
    float v = (c < 768) ? Wih[(size_t)r*768 + c] : Whh[(size_t)r*512 + (c-768)];
    Wg[i] = (f16)v;
    if (c == 0) bias_g[p] = bih[r] + bhh[r];
  }
}

// Precompute all step embeddings: embseq[(b*T + t)*256 + col] (f16)
__global__ __launch_bounds__(256) void k_emb(const int* __restrict__ text,
    const float* __restrict__ embt, f16* __restrict__ embseq){
  int i = blockIdx.x*256 + threadIdx.x;
  if (i < B_*T_*E_){
    int bt = i >> 8, col = i & 255;
    int tok = text[bt];
    embseq[i] = (f16)embt[(size_t)tok*E_ + col];
  }
}

// NEW: Xeh[b] = [emb_0 | h=0]; emb part copied here (h zeroed by memset).
__global__ __launch_bounds__(128) void k_initeh(const f16* __restrict__ embseq, f16* __restrict__ Xeh){
  int b = blockIdx.x, tid = threadIdx.x;
  ((u32*)(Xeh + (size_t)b*XEH))[tid] = ((const u32*)(embseq + ((size_t)(b*T_))*256))[tid];
}

// ---------------- GEMM1 (MFMA, verified): C = A(f32)[M,512] @ Wn(f16)[N,512]^T -> f16[M,N]
__global__ __launch_bounds__(256) void k_sf_mfma(
    const float* __restrict__ A, const f16* __restrict__ Wn, u16* __restrict__ Cd, int N)
{
  int w = threadIdx.x >> 6, lane = threadIdx.x & 63;
  int quad = lane >> 4, l16 = lane & 15;
  int m0 = blockIdx.x * 64;
  int nb = blockIdx.y * 256 + w * 64;
  const float* ap0 = A  + (size_t)(m0 + l16)*512 + quad*8;
  const f16*   bp0 = Wn + (size_t)(nb + l16)*512 + quad*8;
  f32x4 acc[4][4] = {};
  for (int k0=0; k0<512; k0+=32){
    f16x8 bfr[4];
#pragma unroll
    for (int nt=0; nt<4; nt++)
      bfr[nt] = *(const f16x8*)(bp0 + (size_t)nt*16*512 + k0);
#pragma unroll
    for (int f=0; f<4; f++){
      const float* ap = ap0 + (size_t)f*16*512 + k0;
      float4 a0 = *(const float4*)ap;
      float4 a1 = *(const float4*)(ap+4);
      f16x8 afr = { (f16)a0.x,(f16)a0.y,(f16)a0.z,(f16)a0.w,
                    (f16)a1.x,(f16)a1.y,(f16)a1.z,(f16)a1.w };
#pragma unroll
      for (int nt=0; nt<4; nt++)
        acc[f][nt] = __builtin_amdgcn_mfma_f32_16x16x32_f16(afr, bfr[nt], acc[f][nt], 0,0,0);
    }
  }
#pragma unroll
  for (int f=0; f<4; f++)
#pragma unroll
    for (int nt=0; nt<4; nt++)
#pragma unroll
      for (int r=0; r<4; r++){
        int m = m0 + f*16 + quad*4 + r;
        int n = nb + nt*16 + l16;
        Cd[(size_t)m*N + n] = f2h(acc[f][nt][r]);
      }
}

// ---------------- GEMM2: probs = hs @ Wgen^T + bgen (verified)
__global__ __launch_bounds__(256) void gemm_probs(
    const u16* __restrict__ A, const float* __restrict__ W, const float* __restrict__ bias,
    float* __restrict__ Cd, int M, int N, int K)
{
  __shared__ float As[16][64+1];
  __shared__ float Ws[16][64+1];
  const int tid = threadIdx.x;
  const int bm = blockIdx.x*64, bn = blockIdx.y*64;
  const int lr = tid>>2;
  const int lc = (tid&3)*4;
  const int ty = tid>>4, tx = tid&15;
  float acc[4][4];
#pragma unroll
  for (int i=0;i<4;i++)
#pragma unroll
    for (int j=0;j<4;j++) acc[i][j]=0.f;

  for (int k0=0;k0<K;k0+=16){
    ushort4 va = *(const ushort4*)(A + (size_t)(bm+lr)*K + k0 + lc);
    As[lc+0][lr]=h2f(va.x); As[lc+1][lr]=h2f(va.y); As[lc+2][lr]=h2f(va.z); As[lc+3][lr]=h2f(va.w);
    int n = bn + lr;
    if (n < N){
      float4 vw = *(const float4*)(W + (size_t)n*K + k0 + lc);
      Ws[lc+0][lr]=vw.x; Ws[lc+1][lr]=vw.y; Ws[lc+2][lr]=vw.z; Ws[lc+3][lr]=vw.w;
    } else {
      Ws[lc+0][lr]=0.f; Ws[lc+1][lr]=0.f; Ws[lc+2][lr]=0.f; Ws[lc+3][lr]=0.f;
    }
    __syncthreads();
#pragma unroll
    for (int k=0;k<16;k++){
      float a[4], w[4];
#pragma unroll
      for (int i=0;i<4;i++) a[i]=As[k][ty*4+i];
#pragma unroll
      for (int j=0;j<4;j++) w[j]=Ws[k][tx*4+j];
#pragma unroll
      for (int i=0;i<4;i++)
#pragma unroll
        for (int j=0;j<4;j++) acc[i][j] += a[i]*w[j];
    }
    __syncthreads();
  }
#pragma unroll
  for (int i=0;i<4;i++){
    int m = bm + ty*4 + i;
#pragma unroll
    for (int j=0;j<4;j++){
      int n = bn + tx*4 + j;
      if (n < N) Cd[(size_t)m*N + n] = acc[i][j] + bias[n];
    }
  }
}

// ---------------- NEW K1: att (proj+logit, blocks 0..255) + gpart MFMA (blocks 256..271)
__global__ __launch_bounds__(512) void k_step1(
    const u32* __restrict__ WhQ, const u16* __restrict__ sf,
    const f16* __restrict__ Xeh, const float* __restrict__ bh2h,
    const float* __restrict__ wsc, float* __restrict__ logit,
    const f16* __restrict__ WgP, const float* __restrict__ bias_g,
    float* __restrict__ gpart)
{
  const int tid = threadIdx.x;
  const int wid = tid >> 6, lane = tid & 63;
  __shared__ __align__(16) u32 sh_h2[256];
  __shared__ float sh_proj[512];

  if (blockIdx.x < 256){
    const int b = blockIdx.x >> 2;
    const int q = blockIdx.x & 3;
    if (tid < 256) sh_h2[tid] = ((const u32*)(Xeh + (size_t)b*XEH + 256))[tid];
    __syncthreads();
    // proj[n=tid]: 64 iters of u32x4 over WhQ. Wave load = 1KB contiguous. (verified r4)
    {
      const u32* wp = WhQ + ((size_t)tid << 2);
      const u32x4* hp = (const u32x4*)sh_h2;
      float a0=0.f, a1=0.f, a2=0.f, a3=0.f;
#pragma unroll 8
      for (int kq=0; kq<64; kq++){
        u32x4 wq = *(const u32x4*)(wp + ((size_t)kq << 11));
        u32x4 hq = hp[kq];
        a0 = dot2f(wq.x, hq.x, a0);
        a1 = dot2f(wq.y, hq.y, a1);
        a2 = dot2f(wq.z, hq.z, a2);
        a3 = dot2f(wq.w, hq.w, a3);
      }
      sh_proj[tid] = (a0+a1) + (a2+a3) + bh2h[tid];
    }
    __syncthreads();
    // logit: 8 waves x 12 rows; lane owns 8 H-cols (coalesced 1KB row reads). (verified r4)
    {
      float pv[8], wv[8];
#pragma unroll
      for (int j=0;j<8;j++){ pv[j]=sh_proj[lane*8+j]; wv[j]=wsc[lane*8+j]; }
      const int l0 = q*96 + wid*12;
      const f16* sp0 = (const f16*)sf + (((size_t)(b*L_ + l0)) << 9) + lane*8;
#pragma unroll 4
      for (int i=0;i<12;i++){
        f16x8 s = *(const f16x8*)(sp0 + ((size_t)i << 9));
        float v;
        v  = tanh_f((float)s[0]+pv[0])*wv[0];
        v += tanh_f((float)s[1]+pv[1])*wv[1];
        v += tanh_f((float)s[2]+pv[2])*wv[2];
        v += tanh_f((float)s[3]+pv[3])*wv[3];
        v += tanh_f((float)s[4]+pv[4])*wv[4];
        v += tanh_f((float)s[5]+pv[5])*wv[5];
        v += tanh_f((float)s[6]+pv[6])*wv[6];
        v += tanh_f((float)s[7]+pv[7])*wv[7];
        v = wredsum(v);
        if (lane == 0) logit[b*L_ + l0 + i] = v;
      }
    }
  } else {
    // gpart[b][n] = Xeh[b,:768] . WgP[n,:768] + bias_g[n]   (MFMA, k_proj-verified layout)
    const int j = blockIdx.x - 256;     // 0..15
    const int quad = lane >> 4, l16 = lane & 15;
    const int n = j*128 + wid*16 + l16;
    const f16* bp  = WgP + (size_t)n*768 + quad*8;
    const f16* ap0 = Xeh + (size_t)l16*XEH + quad*8;
    f32x4 acc[4] = {};
    for (int k0=0; k0<768; k0+=32){
      f16x8 bfr = *(const f16x8*)(bp + k0);
#pragma unroll
      for (int f=0; f<4; f++){
        f16x8 afr = *(const f16x8*)(ap0 + (size_t)f*16*XEH + k0);
        acc[f] = __builtin_amdgcn_mfma_f32_16x16x32_f16(afr, bfr, acc[f], 0,0,0);
      }
    }
    float bias = bias_g[n];
#pragma unroll
    for (int f=0; f<4; f++)
#pragma unroll
      for (int r=0; r<4; r++){
        int b2 = f*16 + quad*4 + r;
        gpart[(size_t)b2*2048 + n] = acc[f][r] + bias;
      }
  }
}

// ---------------- NEW K2: softmax + gates weighted-sum over sg + LSTM cell.
// grid 256 x 512: block (b = bid>>2, q = bid&3) owns packed gate cols [512q, 512q+512).
__global__ __launch_bounds__(512) void k_step2(
    const float* __restrict__ logit, const u16* __restrict__ sg,
    const float* __restrict__ gpart, const f16* __restrict__ embseq,
    float* __restrict__ cbuf, f16* __restrict__ Xeh, u16* __restrict__ hs, int t)
{
  const int b = blockIdx.x >> 2, q = blockIdx.x & 3;
  const int tid = threadIdx.x;
  const int wid = tid >> 6, lane = tid & 63;
  __shared__ float sh_al[L_];
  __shared__ float sh_red[16];
  __shared__ float sh_gs[2][512];

  // softmax over 384 (verified round-4 pattern)
  float inv;
  {
    float va = (tid < L_) ? logit[b*L_ + tid] : -3.0e38f;
    float m = va;
#pragma unroll
    for (int o=32;o>0;o>>=1) m = fmaxf(m, __shfl_down(m,o,64));
    if (lane==0) sh_red[wid] = m;
    __syncthreads();
    m = fmaxf(fmaxf(fmaxf(sh_red[0],sh_red[1]),fmaxf(sh_red[2],sh_red[3])),
              fmaxf(fmaxf(sh_red[4],sh_red[5]),fmaxf(sh_red[6],sh_red[7])));
    float e = (tid < L_) ? __expf(va - m) : 0.f;
    if (tid < L_) sh_al[tid] = e;
    float ss = wredsum(e);
    if (lane==0) sh_red[8+wid] = ss;
    __syncthreads();
    inv = 1.f/(((sh_red[8]+sh_red[9])+(sh_red[10]+sh_red[11]))
             + ((sh_red[12]+sh_red[13])+(sh_red[14]+sh_red[15])));
  }

  // weighted gate-sum over sg slice: thread = (col-pair cp, l-half lh); coalesced u32 rows
  {
    const int cp = tid & 255, lh = tid >> 8;
    const u32* sp = (const u32*)sg + ((size_t)(b*L_ + lh*192))*1024 + q*256 + cp;
    const float* alp = sh_al + lh*192;
    float a0 = 0.f, a1 = 0.f;
#pragma unroll 8
    for (int l=0;l<192;l++){
      u32 v = sp[(size_t)l*1024];
      f16x2 p2; __builtin_memcpy(&p2,&v,4);
      float al = alp[l];
      a0 += al*(float)p2[0];
      a1 += al*(float)p2[1];
    }
    sh_gs[lh][cp*2  ] = a0;
    sh_gs[lh][cp*2+1] = a1;
  }
  __syncthreads();

  if (tid < 128){
    // local cols tid*4+g  ->  pc = (q*128+tid)*4+g ; gates i,f,g,o adjacent
    const float4 gp = *(const float4*)(gpart + (size_t)b*2048 + q*512 + tid*4);
    float gi = (sh_gs[0][tid*4+0] + sh_gs[1][tid*4+0])*inv + gp.x;
    float gf = (sh_gs[0][tid*4+1] + sh_gs[1][tid*4+1])*inv + gp.y;
    float gg = (sh_gs[0][tid*4+2] + sh_gs[1][tid*4+2])*inv + gp.z;
    float go = (sh_gs[0][tid*4+3] + sh_gs[1][tid*4+3])*inv + gp.w;
    float fi=sigm_f(gi), ff=sigm_f(gf), fg=tanh_f(gg), fo=sigm_f(go);
    const int hd = q*128 + tid;
    size_t ci = ((size_t)b<<9) + hd;
    float cn = ff*cbuf[ci] + fi*fg;
    float hn = fo*tanh_f(cn);
    cbuf[ci] = cn;
    Xeh[(size_t)b*XEH + 256 + hd] = (f16)hn;
    hs[((size_t)(b*T_ + t))*512 + hd] = f2h(hn);
  } else if (q == 0 && tid >= 256 && tid < 384 && (t+1) < T_){
    int c = tid - 256;
    ((u32*)(Xeh + (size_t)b*XEH))[c] =
        ((const u32*)(embseq + ((size_t)(b*T_ + t + 1))*256))[c];
  }
}

// ================= FALLBACK path kernels (round-4 verbatim, verified) =================
__global__ __launch_bounds__(512) void k_att1(
    const u32* __restrict__ WhQ, const u16* __restrict__ sf,
    const f16* __restrict__ Xc, const float* __restrict__ bh2h,
    const float* __restrict__ wsc, float* __restrict__ logit)
{
  const int b   = blockIdx.x >> 2;
  const int q   = blockIdx.x & 3;
  const int tid = threadIdx.x;
  const int wid = tid >> 6, lane = tid & 63;
  __shared__ __align__(16) u32 sh_h2[256];
  __shared__ float sh_proj[512];
  if (tid < 256) sh_h2[tid] = ((const u32*)(Xc + (size_t)b*XROW + 512))[tid];
  __syncthreads();
  {
    const u32* wp = WhQ + ((size_t)tid << 2);
    const u32x4* hp = (const u32x4*)sh_h2;
    float a0=0.f, a1=0.f, a2=0.f, a3=0.f;
#pragma unroll 8
    for (int kq=0; kq<64; kq++){
      u32x4 wq = *(const u32x4*)(wp + ((size_t)kq << 11));
      u32x4 hq = hp[kq];
      a0 = dot2f(wq.x, hq.x, a0);
      a1 = dot2f(wq.y, hq.y, a1);
      a2 = dot2f(wq.z, hq.z, a2);
      a3 = dot2f(wq.w, hq.w, a3);
    }
    sh_proj[tid] = (a0+a1) + (a2+a3) + bh2h[tid];
  }
  __syncthreads();
  {
    float pv[8], wv[8];
#pragma unroll
    for (int j=0;j<8;j++){ pv[j]=sh_proj[lane*8+j]; wv[j]=wsc[lane*8+j]; }
    const int l0 = q*96 + wid*12;
    const f16* sp0 = (const f16*)sf + (((size_t)(b*L_ + l0)) << 9) + lane*8;
#pragma unroll 4
    for (int i=0;i<12;i++){
      f16x8 s = *(const f16x8*)(sp0 + ((size_t)i << 9));
      float v;
      v  = tanh_f((float)s[0]+pv[0])*wv[0];
      v += tanh_f((float)s[1]+pv[1])*wv[1];
      v += tanh_f((float)s[2]+pv[2])*wv[2];
      v += tanh_f((float)s[3]+pv[3])*wv[3];
      v += tanh_f((float)s[4]+pv[4])*wv[4];
      v += tanh_f((float)s[5]+pv[5])*wv[5];
      v += tanh_f((float)s[6]+pv[6])*wv[6];
      v += tanh_f((float)s[7]+pv[7])*wv[7];
      v = wredsum(v);
      if (lane == 0) logit[b*L_ + l0 + i] = v;
    }
  }
}

__global__ __launch_bounds__(512) void k_ctx2(
    const float* __restrict__ logit, const f16* __restrict__ src16,
    f16* __restrict__ Xc)
{
  const int b   = blockIdx.x;
  const int tid = threadIdx.x;
  const int wid = tid >> 6, lane = tid & 63;
  __shared__ float sh_al[L_];
  __shared__ float sh_red[16];
  __shared__ float sh_cp[8][512];
  float inv;
  {
    float va = (tid < L_) ? logit[b*L_ + tid] : -3.0e38f;
    float m = va;
#pragma unroll
    for (int o=32;o>0;o>>=1) m = fmaxf(m, __shfl_down(m,o,64));
    if (lane==0) sh_red[wid] = m;
    __syncthreads();
    m = fmaxf(fmaxf(fmaxf(sh_red[0],sh_red[1]),fmaxf(sh_red[2],sh_red[3])),
              fmaxf(fmaxf(sh_red[4],sh_red[5]),fmaxf(sh_red[6],sh_red[7])));
    float e = (tid < L_) ? __expf(va - m) : 0.f;
    if (tid < L_) sh_al[tid] = e;
    float ss = wredsum(e);
    if (lane==0) sh_red[8+wid] = ss;
    __syncthreads();
    inv = 1.f/(((sh_red[8]+sh_red[9])+(sh_red[10]+sh_red[11]))
             + ((sh_red[12]+sh_red[13])+(sh_red[14]+sh_red[15])));
  }
  {
    float acc[8] = {0.f,0.f,0.f,0.f,0.f,0.f,0.f,0.f};
    const f16* sp0 = src16 + (((size_t)(b*L_ + wid*48)) << 9) + lane*8;
    const float* alp = sh_al + wid*48;
#pragma unroll 4
    for (int i=0;i<48;i++){
      f16x8 v = *(const f16x8*)(sp0 + ((size_t)i << 9));
      float al = alp[i];
#pragma unroll
      for (int e=0;e<8;e++) acc[e] += al*(float)v[e];
    }
#pragma unroll
    for (int e=0;e<8;e++) sh_cp[wid][lane*8+e] = acc[e];
  }
  __syncthreads();
  if (tid < 256){
    int c0 = tid*2;
    float v0 = (((sh_cp[0][c0]+sh_cp[1][c0])+(sh_cp[2][c0]+sh_cp[3][c0]))
              + ((sh_cp[4][c0]+sh_cp[5][c0])+(sh_cp[6][c0]+sh_cp[7][c0])))*inv;
    int c1 = c0+1;
    float v1 = (((sh_cp[0][c1]+sh_cp[1][c1])+(sh_cp[2][c1]+sh_cp[3][c1]))
              + ((sh_cp[4][c1]+sh_cp[5][c1])+(sh_cp[6][c1]+sh_cp[7][c1])))*inv;
    u32 o = (u32)f2h(v0) | ((u32)f2h(v1) << 16);
    ((u32*)(Xc + (size_t)b*XROW))[tid] = o;
  }
}

__global__ __launch_bounds__(256) void k_gates(
    const f16* __restrict__ X, const f16* __restrict__ Wg,
    const float* __restrict__ bias_g, const f16* __restrict__ embseq,
    float* __restrict__ cbuf, f16* __restrict__ Xn, u16* __restrict__ hs, int t)
{
  __shared__ float gbuf[64][17];
  const int tid  = threadIdx.x;
  const int wid  = tid >> 6, lane = tid & 63;
  const int quad = lane >> 4, l16 = lane & 15;
  const int j = blockIdx.x;
  const f16* bp   = Wg + (size_t)(j*16 + l16)*1280 + quad*8;
  const int brow  = wid*16 + l16;
  const f16* actx = X + (size_t)brow*XROW + quad*8;
  const f16* aemb = embseq + (((size_t)brow*T_ + t)<<8) + quad*8;
  const f16* ah   = actx + 512;
  f32x4 acc = {};
#pragma unroll
  for (int k0=0;k0<512;k0+=32)
    acc = __builtin_amdgcn_mfma_f32_16x16x32_f16(*(const f16x8*)(actx+k0), *(const f16x8*)(bp+k0), acc, 0,0,0);
#pragma unroll
  for (int k0=0;k0<256;k0+=32)
    acc = __builtin_amdgcn_mfma_f32_16x16x32_f16(*(const f16x8*)(aemb+k0), *(const f16x8*)(bp+512+k0), acc, 0,0,0);
#pragma unroll
  for (int k0=0;k0<512;k0+=32)
    acc = __builtin_amdgcn_mfma_f32_16x16x32_f16(*(const f16x8*)(ah+k0), *(const f16x8*)(bp+768+k0), acc, 0,0,0);
#pragma unroll
  for (int r=0;r<4;r++) gbuf[wid*16 + quad*4 + r][l16] = acc[r];
  __syncthreads();
  const int b = tid >> 2, hl = tid & 3;
  const int hd = j*4 + hl;
  float gi = gbuf[b][ 0+hl] + bias_g[j*16 +  0 + hl];
  float gf = gbuf[b][ 4+hl] + bias_g[j*16 +  4 + hl];
  float gg = gbuf[b][ 8+hl] + bias_g[j*16 +  8 + hl];
  float go = gbuf[b][12+hl] + bias_g[j*16 + 12 + hl];
  float fi=sigm_f(gi), ff=sigm_f(gf), fg=tanh_f(gg), fo=sigm_f(go);
  size_t ci = ((size_t)b<<9) + hd;
  float cn = ff*cbuf[ci] + fi*fg;
  float hn = fo*tanh_f(cn);
  cbuf[ci] = cn;
  Xn[(size_t)b*XROW + 512 + hd] = (f16)hn;
  hs[(((size_t)(b*T_ + t))<<9) + hd] = f2h(hn);
}

extern "C" void kernel_launch(void* const* d_in, const int* in_sizes, int n_in,
                              void* d_out, int out_size, void* d_ws, size_t ws_size,
                              hipStream_t stream)
{
  const float* src   = (const float*)d_in[0];
  const int*   text  = (const int*)d_in[1];
  const float* embt  = (const float*)d_in[2];
  const float* Wi2h  = (const float*)d_in[3];
  const float* Wh2h  = (const float*)d_in[4];
  const float* bh2h  = (const float*)d_in[5];
  const float* wsc   = (const float*)d_in[6];
  const float* W_ih  = (const float*)d_in[7];
  const float* b_ih  = (const float*)d_in[8];
  const float* W_hh  = (const float*)d_in[9];
  const float* b_hh  = (const float*)d_in[10];
  const float* Wgen  = (const float*)d_in[11];
  const float* bgen  = (const float*)d_in[12];
  float* out = (float*)d_out;

  const size_t NEED_NEW = (size_t)25165824 + 8323072 + 100663296 + 524288 + 524288
                        + 2097152 + 3145728 + 4161536 + 98304 + 98304 + 524288
                        + 131072 + 8192;   // ~138.7 MiB

  if (ws_size >= NEED_NEW){
    // ---------- NEW PATH: 2 kernels/step via sg precompute ----------
    char* p = (char*)d_ws;
    u16*   sfw    = (u16*)p;    p += (size_t)B_*L_*H_*2;        // 25.2 MB
    u16*   hsw    = (u16*)p;    p += (size_t)B_*T_*H_*2;        //  8.3 MB
    u16*   sg     = (u16*)p;    p += (size_t)B_*L_*2048*2;      // 100.7 MB
    u32*   WhQ    = (u32*)p;    p += (size_t)64*512*4*4;        //  0.5 MB
    f16*   Wi2h16 = (f16*)p;    p += (size_t)H_*CS*2;           //  0.5 MB
    f16*   Wcp    = (f16*)p;    p += (size_t)2048*512*2;        //  2.0 MB
    f16*   WgP    = (f16*)p;    p += (size_t)2048*768*2;        //  3.0 MB
    f16*   embseq = (f16*)p;    p += (size_t)B_*T_*E_*2;        //  4.2 MB
    f16*   Xeh    = (f16*)p;    p += (size_t)B_*XEH*2;          //   96 KB
    float* logitw = (float*)p;  p += (size_t)B_*L_*4;           //   98 KB
    float* gpart  = (float*)p;  p += (size_t)B_*2048*4;         //  512 KB
    float* cbuf   = (float*)p;  p += (size_t)B_*H_*4;           //  128 KB
    float* bias_g = (float*)p;  p += (size_t)2048*4;            //    8 KB

    hipMemsetAsync(Xeh,  0, (size_t)B_*XEH*2, stream);
    hipMemsetAsync(cbuf, 0, (size_t)B_*H_*4, stream);

    k_cvt     <<<(H_*CS+255)/256,    256, 0, stream>>>(Wi2h, Wi2h16, H_*CS);
    k_packwhq <<<(64*512*4+255)/256, 256, 0, stream>>>(Wh2h, WhQ);
    k_packwcp <<<(2048*512+255)/256, 256, 0, stream>>>(W_ih, Wcp);
    k_packwgp2<<<(2048*768+255)/256, 256, 0, stream>>>(W_ih, W_hh, b_ih, b_hh, WgP, bias_g);
    k_emb     <<<(B_*T_*E_+255)/256, 256, 0, stream>>>(text, embt, embseq);
    k_initeh  <<<B_, 128, 0, stream>>>(embseq, Xeh);

    k_sf_mfma<<<dim3(384,2), 256, 0, stream>>>(src, Wi2h16, sfw, 512);   // sf
    k_sf_mfma<<<dim3(384,8), 256, 0, stream>>>(src, Wcp,    sg,  2048);  // sg

    for (int t=0; t<T_; t++){
      k_step1<<<272, 512, 0, stream>>>(WhQ, sfw, Xeh, bh2h, wsc, logitw, WgP, bias_g, gpart);
      k_step2<<<256, 512, 0, stream>>>(logitw, sg, gpart, embseq, cbuf, Xeh, hsw, t);
    }

    dim3 g2(B_*T_/64, (NC+63)/64);
    gemm_probs<<<g2, 256, 0, stream>>>(hsw, Wgen, bgen, out, B_*T_, NC, H_);
  } else {
    // ---------- FALLBACK: round-4 verified 3-kernel path ----------
    char* p = (char*)d_ws;
    u16*   sfw    = (u16*)p;    p += (size_t)B_*L_*H_*2;
    u16*   hsw    = (u16*)p;    p += (size_t)B_*T_*H_*2;
    f16*   src16  = (f16*)p;    p += (size_t)B_*L_*CS*2;
    u32*   WhQ    = (u32*)p;    p += (size_t)64*512*4*4;
    f16*   Wi2h16 = (f16*)p;    p += (size_t)H_*CS*2;
    f16*   WgF    = (f16*)p;    p += (size_t)2048*1280*2;
    f16*   embseq = (f16*)p;    p += (size_t)B_*T_*E_*2;
    f16*   X0     = (f16*)p;    p += (size_t)B_*XROW*2;
    f16*   X1     = (f16*)p;    p += (size_t)B_*XROW*2;
    float* logitw = (float*)p;  p += (size_t)B_*L_*4;
    float* cbuf   = (float*)p;  p += (size_t)B_*H_*4;
    float* bias_g = (float*)p;  p += (size_t)2048*4;

    hipMemsetAsync(X0,   0, (size_t)B_*XROW*2*2, stream);
    hipMemsetAsync(cbuf, 0, (size_t)B_*H_*4, stream);

    k_cvt    <<<(H_*CS+255)/256,    256, 0, stream>>>(Wi2h, Wi2h16, H_*CS);
    k_cvt    <<<(B_*L_*CS+255)/256, 256, 0, stream>>>(src, src16, B_*L_*CS);
    k_packwhq<<<(64*512*4+255)/256, 256, 0, stream>>>(Wh2h, WhQ);
    k_packwg <<<(2048*1280+255)/256,256, 0, stream>>>(W_ih, W_hh, b_ih, b_hh, WgF, bias_g);
    k_emb    <<<(B_*T_*E_+255)/256, 256, 0, stream>>>(text, embt, embseq);

    k_sf_mfma<<<dim3(384,2), 256, 0, stream>>>(src, Wi2h16, sfw, 512);

    for (int t=0; t<T_; t++){
      f16* Xc = (t & 1) ? X1 : X0;
      f16* Xn = (t & 1) ? X0 : X1;
      k_att1<<<256, 512, 0, stream>>>(WhQ, sfw, Xc, bh2h, wsc, logitw);
      k_ctx2<<<64, 512, 0, stream>>>(logitw, src16, Xc);
      k_gates<<<128, 256, 0, stream>>>(Xc, WgF, bias_g, embseq, cbuf, Xn, hsw, t);
    }

    dim3 g2(B_*T_/64, (NC+63)/64);
    gemm_probs<<<g2, 256, 0, stream>>>(hsw, Wgen, bgen, out, B_*T_, NC, H_);
  }
}

// Round 6
// 6085.073 us; speedup vs baseline: 1.1200x; 1.1200x over previous
//
#include <hip/hip_runtime.h>

typedef unsigned short u16;
typedef unsigned int   u32;
typedef _Float16 f16;
typedef f16   f16x2 __attribute__((ext_vector_type(2)));
typedef f16   f16x8 __attribute__((ext_vector_type(8)));
typedef float f32x4 __attribute__((ext_vector_type(4)));
typedef u32   u32x4 __attribute__((ext_vector_type(4)));

#define B_  64
#define L_  384
#define CS  512   // SRC_DIM
#define H_  512
#define E_  256
#define NC  250
#define T_  127
#define MSHIFT 20.0f   // fixed softmax shift; |logit| <= ||wscore||_1 ~ 20.4 << 88

__device__ __forceinline__ float h2f(u16 u){ f16 h; __builtin_memcpy(&h,&u,2); return (float)h; }
__device__ __forceinline__ u16  f2h(float f){ f16 h=(f16)f; u16 u; __builtin_memcpy(&u,&h,2); return u; }
__device__ __forceinline__ float wredsum(float v){
#pragma unroll
  for (int o=32;o>0;o>>=1) v += __shfl_down(v, o, 64);
  return v;
}
__device__ __forceinline__ float tanh_f(float x){
  x = fminf(fmaxf(x, -15.f), 15.f);
  float e = __expf(2.f*x);
  return (e-1.f)/(e+1.f);
}
__device__ __forceinline__ float sigm_f(float x){
  x = fminf(fmaxf(x, -30.f), 30.f);
  return 1.f/(1.f+__expf(-x));
}
__device__ __forceinline__ float dot2f(u32 a, u32 b, float c){
  f16x2 x, y; __builtin_memcpy(&x,&a,4); __builtin_memcpy(&y,&b,4);
#if __has_builtin(__builtin_amdgcn_fdot2)
  return __builtin_amdgcn_fdot2(x, y, c, false);
#else
  return c + (float)x[0]*(float)y[0] + (float)x[1]*(float)y[1];
#endif
}

// ---------------- one-time converters / packers ----------------
__global__ __launch_bounds__(256) void k_cvt(const float* __restrict__ in, f16* __restrict__ o, int n){
  int i = blockIdx.x*256 + threadIdx.x;
  if (i < n) o[i] = (f16)in[i];
}

// Quad-k-pair-packed Wh2h (verified round 4):
// WhQ[((kq*512)+n)*4 + e] = (Wh2h[n][8kq+2e], Wh2h[n][8kq+2e+1]) as f16-pair u32.
__global__ __launch_bounds__(256) void k_packwhq(const float* __restrict__ Wh, u32* __restrict__ Wq){
  int i = blockIdx.x*256 + threadIdx.x;   // over 64*512*4
  if (i < 64*512*4){
    int kq = i >> 11, n = (i >> 2) & 511, e = i & 3;
    int k = kq*8 + e*2;
    u32 lo = f2h(Wh[(size_t)n*512 + k]);
    u32 hi = f2h(Wh[(size_t)n*512 + k + 1]);
    Wq[i] = lo | (hi<<16);
  }
}

// ctx-part gates weights (verified round 5): row pc = hd*4+g <-> orig r = g*512+hd; k in [0,512)
__global__ __launch_bounds__(256) void k_packwcp(const float* __restrict__ Wih, f16* __restrict__ Wcp){
  int i = blockIdx.x*256 + threadIdx.x;   // over 2048*512
  if (i < 2048*512){
    int pc = i >> 9, k = i & 511;
    int r = (pc&3)*512 + (pc>>2);
    Wcp[i] = (f16)Wih[(size_t)r*768 + k];
  }
}

// [emb|h]-part gates weights (verified round 5). WgP[pc][k'] with r=(pc&3)*512+(pc>>2):
// k'<256 -> W_ih[r][512+k'] ; k'>=256 -> W_hh[r][k'-256]. bias_g[pc]=bih[r]+bhh[r].
__global__ __launch_bounds__(256) void k_packwgp2(const float* __restrict__ Wih,
    const float* __restrict__ Whh, const float* __restrict__ bih, const float* __restrict__ bhh,
    f16* __restrict__ WgP, float* __restrict__ bias_g){
  int i = blockIdx.x*256 + threadIdx.x;   // over 2048*768
  if (i < 2048*768){
    int pc = i / 768, k = i - pc*768;
    int r = (pc&3)*512 + (pc>>2);
    float v = (k < 256) ? Wih[(size_t)r*768 + 512 + k] : Whh[(size_t)r*512 + (k-256)];
    WgP[i] = (f16)v;
    if (k == 0) bias_g[pc] = bih[r] + bhh[r];
  }
}

// Precompute all step embeddings: embseq[(b*T + t)*256 + col] (f16)
__global__ __launch_bounds__(256) void k_emb(const int* __restrict__ text,
    const float* __restrict__ embt, f16* __restrict__ embseq){
  int i = blockIdx.x*256 + threadIdx.x;
  if (i < B_*T_*E_){
    int bt = i >> 8, col = i & 255;
    int tok = text[bt];
    embseq[i] = (f16)embt[(size_t)tok*E_ + col];
  }
}

// ---------------- GEMM1 (MFMA, verified): C = A(f32)[M,512] @ Wn(f16)[N,512]^T -> f16[M,N]
__global__ __launch_bounds__(256) void k_sf_mfma(
    const float* __restrict__ A, const f16* __restrict__ Wn, u16* __restrict__ Cd, int N)
{
  int w = threadIdx.x >> 6, lane = threadIdx.x & 63;
  int quad = lane >> 4, l16 = lane & 15;
  int m0 = blockIdx.x * 64;
  int nb = blockIdx.y * 256 + w * 64;
  const float* ap0 = A  + (size_t)(m0 + l16)*512 + quad*8;
  const f16*   bp0 = Wn + (size_t)(nb + l16)*512 + quad*8;
  f32x4 acc[4][4] = {};
  for (int k0=0; k0<512; k0+=32){
    f16x8 bfr[4];
#pragma unroll
    for (int nt=0; nt<4; nt++)
      bfr[nt] = *(const f16x8*)(bp0 + (size_t)nt*16*512 + k0);
#pragma unroll
    for (int f=0; f<4; f++){
      const float* ap = ap0 + (size_t)f*16*512 + k0;
      float4 a0 = *(const float4*)ap;
      float4 a1 = *(const float4*)(ap+4);
      f16x8 afr = { (f16)a0.x,(f16)a0.y,(f16)a0.z,(f16)a0.w,
                    (f16)a1.x,(f16)a1.y,(f16)a1.z,(f16)a1.w };
#pragma unroll
      for (int nt=0; nt<4; nt++)
        acc[f][nt] = __builtin_amdgcn_mfma_f32_16x16x32_f16(afr, bfr[nt], acc[f][nt], 0,0,0);
    }
  }
#pragma unroll
  for (int f=0; f<4; f++)
#pragma unroll
    for (int nt=0; nt<4; nt++)
#pragma unroll
      for (int r=0; r<4; r++){
        int m = m0 + f*16 + quad*4 + r;
        int n = nb + nt*16 + l16;
        Cd[(size_t)m*N + n] = f2h(acc[f][nt][r]);
      }
}

// ---------------- probs GEMM (MFMA): out = hs(f16)[8128,512] @ Wgen16[256pad,512]^T + bgen
__global__ __launch_bounds__(256) void k_probs_mfma(
    const u16* __restrict__ A, const f16* __restrict__ Wn,
    const float* __restrict__ bias, float* __restrict__ Cd)
{
  int w = threadIdx.x >> 6, lane = threadIdx.x & 63;
  int quad = lane >> 4, l16 = lane & 15;
  int m0 = blockIdx.x * 64;
  int nb = w * 64;
  const f16* ap0 = (const f16*)A + (size_t)(m0 + l16)*512 + quad*8;
  const f16* bp0 = Wn + (size_t)(nb + l16)*512 + quad*8;
  f32x4 acc[4][4] = {};
  for (int k0=0; k0<512; k0+=32){
    f16x8 bfr[4];
#pragma unroll
    for (int nt=0; nt<4; nt++)
      bfr[nt] = *(const f16x8*)(bp0 + (size_t)nt*16*512 + k0);
#pragma unroll
    for (int f=0; f<4; f++){
      f16x8 afr = *(const f16x8*)(ap0 + (size_t)f*16*512 + k0);
#pragma unroll
      for (int nt=0; nt<4; nt++)
        acc[f][nt] = __builtin_amdgcn_mfma_f32_16x16x32_f16(afr, bfr[nt], acc[f][nt], 0,0,0);
    }
  }
#pragma unroll
  for (int f=0; f<4; f++)
#pragma unroll
    for (int nt=0; nt<4; nt++)
#pragma unroll
      for (int r=0; r<4; r++){
        int m = m0 + f*16 + quad*4 + r;
        int n = nb + nt*16 + l16;
        if (n < NC) Cd[(size_t)m*NC + n] = acc[f][nt][r] + bias[n];
      }
}

// ---------------- K1: att (proj+logit+e+partial ctx/den, blocks 0..255)
//                      + gpart MFMA ([emb|h] gates part, blocks 256..271)
__global__ __launch_bounds__(512) void k_stepA(
    const u32* __restrict__ WhQ, const u16* __restrict__ sf,
    const f16* __restrict__ src16, const f16* __restrict__ hbuf,
    const float* __restrict__ bh2h, const float* __restrict__ wsc,
    const f16* __restrict__ WgP, const float* __restrict__ bias_g,
    const f16* __restrict__ embseq,
    float* __restrict__ ctxp, float* __restrict__ denp,
    float* __restrict__ gpart, int t)
{
  const int tid = threadIdx.x;
  const int wid = tid >> 6, lane = tid & 63;

  if (blockIdx.x < 256){
    const int b = blockIdx.x >> 2;
    const int q = blockIdx.x & 3;
    __shared__ __align__(16) u32 sh_h2[256];
    __shared__ float sh_proj[512];
    __shared__ float sh_e[96];
    __shared__ float sh_cp[8][512];

    if (tid < 256) sh_h2[tid] = ((const u32*)(hbuf + (size_t)b*512))[tid];
    __syncthreads();
    // proj[n=tid]: 64 iters of u32x4 over WhQ (wave load = 1KB contiguous, verified r4)
    {
      const u32* wp = WhQ + ((size_t)tid << 2);
      const u32x4* hp = (const u32x4*)sh_h2;
      float a0=0.f, a1=0.f, a2=0.f, a3=0.f;
#pragma unroll 8
      for (int kq=0; kq<64; kq++){
        u32x4 wq = *(const u32x4*)(wp + ((size_t)kq << 11));
        u32x4 hq = hp[kq];
        a0 = dot2f(wq.x, hq.x, a0);
        a1 = dot2f(wq.y, hq.y, a1);
        a2 = dot2f(wq.z, hq.z, a2);
        a3 = dot2f(wq.w, hq.w, a3);
      }
      sh_proj[tid] = (a0+a1) + (a2+a3) + bh2h[tid];
    }
    __syncthreads();
    // logit rows (verified r4) + fixed-shift exp
    {
      float pv[8], wv[8];
#pragma unroll
      for (int j=0;j<8;j++){ pv[j]=sh_proj[lane*8+j]; wv[j]=wsc[lane*8+j]; }
      const int l0 = q*96 + wid*12;
      const f16* sp0 = (const f16*)sf + (((size_t)(b*L_ + l0)) << 9) + lane*8;
#pragma unroll 4
      for (int i=0;i<12;i++){
        f16x8 s = *(const f16x8*)(sp0 + ((size_t)i << 9));
        float v;
        v  = tanh_f((float)s[0]+pv[0])*wv[0];
        v += tanh_f((float)s[1]+pv[1])*wv[1];
        v += tanh_f((float)s[2]+pv[2])*wv[2];
        v += tanh_f((float)s[3]+pv[3])*wv[3];
        v += tanh_f((float)s[4]+pv[4])*wv[4];
        v += tanh_f((float)s[5]+pv[5])*wv[5];
        v += tanh_f((float)s[6]+pv[6])*wv[6];
        v += tanh_f((float)s[7]+pv[7])*wv[7];
        v = wredsum(v);
        if (lane == 0) sh_e[wid*12 + i] = __expf(v - MSHIFT);
      }
    }
    __syncthreads();
    // den partial (wave 0)
    if (wid == 0){
      float v = sh_e[lane] + (lane < 32 ? sh_e[64+lane] : 0.f);
      v = wredsum(v);
      if (lane == 0) denp[q*64 + b] = v;
    }
    // partial ctx': wave w rows (local) 12w..12w+11, lane owns 8 cols (coalesced 1KB rows)
    {
      float acc[8] = {0.f,0.f,0.f,0.f,0.f,0.f,0.f,0.f};
      const f16* sp0 = src16 + (((size_t)(b*L_ + q*96 + wid*12)) << 9) + lane*8;
      const float* alp = sh_e + wid*12;
#pragma unroll 4
      for (int i=0;i<12;i++){
        f16x8 v = *(const f16x8*)(sp0 + ((size_t)i << 9));
        float al = alp[i];
#pragma unroll
        for (int e=0;e<8;e++) acc[e] += al*(float)v[e];
      }
#pragma unroll
      for (int e=0;e<8;e++) sh_cp[wid][lane*8+e] = acc[e];
    }
    __syncthreads();
    if (tid < 256){
      int c0 = tid*2;
      float v0 = (((sh_cp[0][c0]+sh_cp[1][c0])+(sh_cp[2][c0]+sh_cp[3][c0]))
                + ((sh_cp[4][c0]+sh_cp[5][c0])+(sh_cp[6][c0]+sh_cp[7][c0])));
      int c1 = c0+1;
      float v1 = (((sh_cp[0][c1]+sh_cp[1][c1])+(sh_cp[2][c1]+sh_cp[3][c1]))
                + ((sh_cp[4][c1]+sh_cp[5][c1])+(sh_cp[6][c1]+sh_cp[7][c1])));
      float2 o; o.x = v0; o.y = v1;
      *(float2*)(ctxp + (((size_t)(q*64 + b)) << 9) + c0) = o;
    }
  } else {
    // gpart[b][n] = [emb_t(b) | h(b)] . WgP[n,:768] + bias_g[n]
    const int j = blockIdx.x - 256;     // 0..15
    const int quad = lane >> 4, l16 = lane & 15;
    const int n = j*128 + wid*16 + l16;
    const f16* bp = WgP + (size_t)n*768 + quad*8;
    f32x4 acc[4] = {};
    // emb part (k' in [0,256))
    for (int k0=0; k0<256; k0+=32){
      f16x8 bfr = *(const f16x8*)(bp + k0);
#pragma unroll
      for (int f=0; f<4; f++){
        int br = f*16 + l16;
        f16x8 afr = *(const f16x8*)(embseq + (((size_t)(br*T_ + t)) << 8) + quad*8 + k0);
        acc[f] = __builtin_amdgcn_mfma_f32_16x16x32_f16(afr, bfr, acc[f], 0,0,0);
      }
    }
    // h part (k' in [256,768))
    for (int k0=0; k0<512; k0+=32){
      f16x8 bfr = *(const f16x8*)(bp + 256 + k0);
#pragma unroll
      for (int f=0; f<4; f++){
        int br = f*16 + l16;
        f16x8 afr = *(const f16x8*)(hbuf + (size_t)br*512 + quad*8 + k0);
        acc[f] = __builtin_amdgcn_mfma_f32_16x16x32_f16(afr, bfr, acc[f], 0,0,0);
      }
    }
    float bias = bias_g[n];
#pragma unroll
    for (int f=0; f<4; f++)
#pragma unroll
      for (int r=0; r<4; r++){
        int b2 = f*16 + quad*4 + r;
        gpart[((size_t)b2 << 11) + n] = acc[f][r] + bias;
      }
  }
}

// ---------------- K2: combine ctx partials -> LDS f16, ctx-gates MFMA, LSTM cell.
// grid 128 x 256: block j owns h-dims [4j,4j+4) x 4 gates (packed rows j*16..j*16+16).
__global__ __launch_bounds__(256) void k_stepB(
    const float* __restrict__ ctxp, const float* __restrict__ denp,
    const float* __restrict__ gpart, const f16* __restrict__ Wcp,
    float* __restrict__ cbuf, f16* __restrict__ hbuf, u16* __restrict__ hs, int t)
{
  __shared__ f16   sh_ctx[64][520];   // +8 pad: 2-way banks on ds_read_b128
  __shared__ float gbuf[64][17];
  __shared__ float sh_inv[64];
  const int tid = threadIdx.x;
  const int wid = tid >> 6, lane = tid & 63;
  const int quad = lane >> 4, l16 = lane & 15;
  const int j = blockIdx.x;

  if (tid < 64)
    sh_inv[tid] = 1.f/(((denp[tid] + denp[64+tid]) + (denp[128+tid] + denp[192+tid])));
  __syncthreads();

  // combine 4 ctx' slices -> normalized f16 ctx (8192 float4 slots / 256 thr = 32 iters)
#pragma unroll 4
  for (int i=0;i<32;i++){
    int flat = tid + i*256;
    int b = flat >> 7, c4 = flat & 127;
    const float* base = ctxp + ((size_t)b << 9) + (c4 << 2);
    float4 v0 = *(const float4*)(base);
    float4 v1 = *(const float4*)(base + (64<<9));
    float4 v2 = *(const float4*)(base + (128<<9));
    float4 v3 = *(const float4*)(base + (192<<9));
    float inv = sh_inv[b];
    int c = c4*4;
    sh_ctx[b][c+0] = (f16)(((v0.x+v1.x)+(v2.x+v3.x))*inv);
    sh_ctx[b][c+1] = (f16)(((v0.y+v1.y)+(v2.y+v3.y))*inv);
    sh_ctx[b][c+2] = (f16)(((v0.z+v1.z)+(v2.z+v3.z))*inv);
    sh_ctx[b][c+3] = (f16)(((v0.w+v1.w)+(v2.w+v3.w))*inv);
  }
  __syncthreads();

  // ctx-gates MFMA: B rows = packed rows j*16+l16 of Wcp; wave wid covers batches wid*16..+15
  {
    const f16* bp = Wcp + (size_t)(j*16 + l16)*512 + quad*8;
    const f16* ap = &sh_ctx[wid*16 + l16][quad*8];
    f32x4 acc = {};
#pragma unroll
    for (int k0=0; k0<512; k0+=32)
      acc = __builtin_amdgcn_mfma_f32_16x16x32_f16(*(const f16x8*)(ap + k0),
                                                   *(const f16x8*)(bp + k0), acc, 0,0,0);
#pragma unroll
    for (int r=0;r<4;r++) gbuf[wid*16 + quad*4 + r][l16] = acc[r];
  }
  __syncthreads();

  // cell: thread (b2, hl); packed col l16 = hl*4 + g; gpart float4 = 4 gates of (b2, hd)
  {
    const int b2 = tid >> 2, hl = tid & 3;
    const int hd = j*4 + hl;
    float4 gp = *(const float4*)(gpart + ((size_t)b2 << 11) + (size_t)hd*4);
    float gi = gbuf[b2][hl*4+0] + gp.x;
    float gf = gbuf[b2][hl*4+1] + gp.y;
    float gg = gbuf[b2][hl*4+2] + gp.z;
    float go = gbuf[b2][hl*4+3] + gp.w;
    float fi=sigm_f(gi), ff=sigm_f(gf), fg=tanh_f(gg), fo=sigm_f(go);
    size_t ci = ((size_t)b2 << 9) + hd;
    float cn = ff*cbuf[ci] + fi*fg;
    float hn = fo*tanh_f(cn);
    cbuf[ci] = cn;
    hbuf[((size_t)b2 << 9) + hd] = (f16)hn;
    hs[((size_t)(b2*T_ + t)) * 512 + hd] = f2h(hn);
  }
}

extern "C" void kernel_launch(void* const* d_in, const int* in_sizes, int n_in,
                              void* d_out, int out_size, void* d_ws, size_t ws_size,
                              hipStream_t stream)
{
  const float* src   = (const float*)d_in[0];
  const int*   text  = (const int*)d_in[1];
  const float* embt  = (const float*)d_in[2];
  const float* Wi2h  = (const float*)d_in[3];
  const float* Wh2h  = (const float*)d_in[4];
  const float* bh2h  = (const float*)d_in[5];
  const float* wsc   = (const float*)d_in[6];
  const float* W_ih  = (const float*)d_in[7];
  const float* b_ih  = (const float*)d_in[8];
  const float* W_hh  = (const float*)d_in[9];
  const float* b_hh  = (const float*)d_in[10];
  const float* Wgen  = (const float*)d_in[11];
  const float* bgen  = (const float*)d_in[12];
  float* out = (float*)d_out;

  // Workspace (~70 MB)
  char* p = (char*)d_ws;
  u16*   sfw    = (u16*)p;    p += (size_t)B_*L_*H_*2;        // 25.2 MB
  u16*   hsw    = (u16*)p;    p += (size_t)B_*T_*H_*2;        //  8.3 MB
  f16*   src16  = (f16*)p;    p += (size_t)B_*L_*CS*2;        // 25.2 MB
  u32*   WhQ    = (u32*)p;    p += (size_t)64*512*4*4;        //  0.5 MB
  f16*   Wi2h16 = (f16*)p;    p += (size_t)H_*CS*2;           //  0.5 MB
  f16*   Wcp    = (f16*)p;    p += (size_t)2048*512*2;        //  2.0 MB
  f16*   WgP    = (f16*)p;    p += (size_t)2048*768*2;        //  3.0 MB
  f16*   Wgen16 = (f16*)p;    p += (size_t)256*512*2;         //  0.25 MB
  f16*   embseq = (f16*)p;    p += (size_t)B_*T_*E_*2;        //  4.2 MB
  f16*   hbuf   = (f16*)p;    p += (size_t)B_*H_*2;           //   64 KB
  float* ctxp   = (float*)p;  p += (size_t)4*B_*512*4;        //  512 KB
  float* denp   = (float*)p;  p += (size_t)256*4;             //    1 KB
  float* gpart  = (float*)p;  p += (size_t)B_*2048*4;         //  512 KB
  float* cbuf   = (float*)p;  p += (size_t)B_*H_*4;           //  128 KB
  float* bias_g = (float*)p;  p += (size_t)2048*4;            //    8 KB

  hipMemsetAsync(hbuf,   0, (size_t)B_*H_*2, stream);
  hipMemsetAsync(cbuf,   0, (size_t)B_*H_*4, stream);
  hipMemsetAsync(Wgen16, 0, (size_t)256*512*2, stream);

  // one-time conversions / packing
  k_cvt     <<<(H_*CS+255)/256,    256, 0, stream>>>(Wi2h, Wi2h16, H_*CS);
  k_cvt     <<<(B_*L_*CS+255)/256, 256, 0, stream>>>(src, src16, B_*L_*CS);
  k_cvt     <<<(NC*512+255)/256,   256, 0, stream>>>(Wgen, (f16*)Wgen16, NC*512);
  k_packwhq <<<(64*512*4+255)/256, 256, 0, stream>>>(Wh2h, WhQ);
  k_packwcp <<<(2048*512+255)/256, 256, 0, stream>>>(W_ih, Wcp);
  k_packwgp2<<<(2048*768+255)/256, 256, 0, stream>>>(W_ih, W_hh, b_ih, b_hh, WgP, bias_g);
  k_emb     <<<(B_*T_*E_+255)/256, 256, 0, stream>>>(text, embt, embseq);

  // sf = src @ Wi2h^T  (MFMA f16)
  k_sf_mfma<<<dim3(384,2), 256, 0, stream>>>(src, Wi2h16, sfw, 512);

  // decode loop: 2 kernels per step
  for (int t=0; t<T_; t++){
    k_stepA<<<272, 512, 0, stream>>>(WhQ, sfw, src16, hbuf, bh2h, wsc,
                                     WgP, bias_g, embseq, ctxp, denp, gpart, t);
    k_stepB<<<128, 256, 0, stream>>>(ctxp, denp, gpart, Wcp, cbuf, hbuf, hsw, t);
  }

  // probs = hs @ Wgen^T + bgen (MFMA)
  k_probs_mfma<<<127, 256, 0, stream>>>(hsw, Wgen16, bgen, out);
}